// Round 7
// baseline (137.592 us; speedup 1.0000x reference)
//
#include <hip/hip_runtime.h>
#include <math.h>

#define NB 11
#define PAD 5
#define DIM 128
#define NN 121        // NB*NB
#define S_TOT 484     // HEADS*NN
#define IMG 64
#define TILE 8        // pixels per block (x-contiguous)
#define PDIM 74       // IMG + 2*PAD
#define LN_EPS 1e-5f

// Prologue: zero-padded kv copy into workspace: pkv[b][py][px][c], py,px in [0,74)
__global__ __launch_bounds__(128) void pad_kernel(const float* __restrict__ kv,
                                                  float* __restrict__ pkv) {
    const int row = blockIdx.x;            // 0 .. 2*74*74-1
    const int b  = row / (PDIM * PDIM);
    const int rr = row - b * PDIM * PDIM;
    const int py = rr / PDIM;
    const int px = rr - py * PDIM;
    const int ky = py - PAD, kx = px - PAD;
    float v = 0.f;
    if ((unsigned)ky < (unsigned)IMG && (unsigned)kx < (unsigned)IMG)
        v = kv[(((size_t)b * IMG + ky) * IMG + kx) * DIM + threadIdx.x];
    pkv[(size_t)row * DIM + threadIdx.x] = v;
}

// Single-arg launch bounds ONLY: (512,8)/(256,8) capped VGPR at 32 and spilled.
template<bool PADDED>
__global__ __launch_bounds__(512) void nca_kernel(
    const float* __restrict__ q, const float* __restrict__ kvsrc,
    const float* __restrict__ pos, const float* __restrict__ w,
    const float* __restrict__ bias, const float* __restrict__ gam,
    const float* __restrict__ bet, float* __restrict__ out)
{
    const int tile = blockIdx.x;         // 1024 tiles of 8 pixels along x
    const int pix0 = tile * TILE;
    const int x0 = pix0 & 63;
    const int y  = (pix0 >> 6) & 63;
    const int b  = pix0 >> 12;
    const int tid = threadIdx.x;

    __shared__ float qs[TILE][DIM];      // q, later x = q + gelu(mlp)
    __shared__ float sc[S_TOT][TILE];    // scores, s-major
    __shared__ float part[4][TILE][DIM]; // per-K-group partial sums

    // ---- stage q for 8 pixels (4 KB, coalesced) ----
    for (int i = tid; i < TILE * DIM; i += 512)
        qs[i >> 7][i & 127] = q[(size_t)pix0 * DIM + i];
    __syncthreads();

    // ---- phase A: scores. 16-lane group = one kv row (8 chans/lane) ----
    // task T = iter*32 + 4*wave + grp; pix = T&7 (invariant), p = 4*iter + c0.
    // lane l16: kv chans 8*l16..+7, r = l16>>2, s = 4p+r, h = s/121 (incremental),
    // q chans h*32 + 8*(l16&3)..+7. 4-lane shfl reduction -> score.
    {
        const int wv  = tid >> 6;          // 0..7
        const int grp = (tid >> 4) & 3;
        const int l16 = tid & 15;
        const int gid = 4 * wv + grp;      // 0..31
        const int pix = gid & 7;
        const int c0  = gid >> 3;          // 0..3
        const int r   = l16 >> 2;
        const int dq  = 8 * (l16 & 3);
        const int ch  = 8 * l16;
        const int xpix = x0 + pix;

        int p = c0, i = 0, j = c0;
        int h = 0, rem = 4 * c0 + r;

        const float* kvb = PADDED
            ? kvsrc + (size_t)b * PDIM * PDIM * DIM + ch
            : kvsrc + (size_t)b * IMG * IMG * DIM + ch;
        const float* posb = pos + ch;

        for (int it = 0; it < 31; ++it) {
            if (p <= 120) {
                float4 k0, k1;
                if (PADDED) {
                    const float* kp = kvb + (size_t)((y + i) * PDIM + (xpix + j)) * DIM;
                    k0 = *(const float4*)(kp);
                    k1 = *(const float4*)(kp + 4);
                } else {
                    const int ky = y + i - PAD, kx = xpix + j - PAD;
                    if (((unsigned)ky < (unsigned)IMG) && ((unsigned)kx < (unsigned)IMG)) {
                        const float* kp = kvb + (size_t)(ky * IMG + kx) * DIM;
                        k0 = *(const float4*)(kp);
                        k1 = *(const float4*)(kp + 4);
                    } else {
                        k0 = make_float4(0.f, 0.f, 0.f, 0.f);
                        k1 = make_float4(0.f, 0.f, 0.f, 0.f);
                    }
                }
                const float4 p0 = *(const float4*)(posb + (size_t)p * DIM);
                const float4 p1 = *(const float4*)(posb + (size_t)p * DIM + 4);
                const float* qp = &qs[pix][h * 32 + dq];
                const float4 q0 = *(const float4*)(qp);
                const float4 q1 = *(const float4*)(qp + 4);
                float t = (k0.x + p0.x) * q0.x + (k0.y + p0.y) * q0.y
                        + (k0.z + p0.z) * q0.z + (k0.w + p0.w) * q0.w
                        + (k1.x + p1.x) * q1.x + (k1.y + p1.y) * q1.y
                        + (k1.z + p1.z) * q1.z + (k1.w + p1.w) * q1.w;
                t += __shfl_xor(t, 1, 64);
                t += __shfl_xor(t, 2, 64);
                if ((l16 & 3) == 0) sc[4 * p + r][pix] = t;
            }
            // incremental index updates (no divisions in the loop)
            p += 4; j += 4;
            if (j >= NB) { j -= NB; ++i; }
            rem += 16;
            if (rem >= NN) { rem -= NN; ++h; }
        }
    }
    __syncthreads();

    // ---- phase B: MLP. group g owns K-rows [g*121, +121), all 8 pixels ----
    const int c = tid & 127;
    const int g = tid >> 7;              // 0..3
    {
        const float* wc  = w + (size_t)(g * NN) * DIM + c;
        const float* scp = &sc[g * NN][0];
        float a0 = 0.f, a1 = 0.f, a2 = 0.f, a3 = 0.f;
        float a4 = 0.f, a5 = 0.f, a6 = 0.f, a7 = 0.f;
        #pragma unroll 2
        for (int s = 0; s < NN; ++s) {
            const float wv = wc[(size_t)s * DIM];                // coalesced
            const float4 sA = *(const float4*)(scp + s * 8);     // broadcast
            const float4 sB = *(const float4*)(scp + s * 8 + 4); // broadcast
            a0 += sA.x * wv; a1 += sA.y * wv; a2 += sA.z * wv; a3 += sA.w * wv;
            a4 += sB.x * wv; a5 += sB.y * wv; a6 += sB.z * wv; a7 += sB.w * wv;
        }
        part[g][0][c] = a0; part[g][1][c] = a1;
        part[g][2][c] = a2; part[g][3][c] = a3;
        part[g][4][c] = a4; part[g][5][c] = a5;
        part[g][6][c] = a6; part[g][7][c] = a7;
    }
    __syncthreads();

    // ---- epilogue: reduce 4 partials, bias, exact GELU, residual ----
    for (int idx = tid; idx < TILE * DIM; idx += 512) {
        const int pix = idx >> 7, cc = idx & 127;
        float v = part[0][pix][cc] + part[1][pix][cc]
                + part[2][pix][cc] + part[3][pix][cc] + bias[cc];
        const float gl = 0.5f * v * (1.f + erff(v * 0.70710678118654752f));
        qs[pix][cc] += gl;               // x = q + gelu(mlp)
    }
    __syncthreads();

    // ---- LayerNorm: wave wid owns pixel wid ----
    {
        const int lane = tid & 63, wid = tid >> 6;
        const float v0 = qs[wid][lane], v1 = qs[wid][lane + 64];
        float sum = v0 + v1;
        #pragma unroll
        for (int off = 1; off < 64; off <<= 1) sum += __shfl_xor(sum, off, 64);
        const float mean = sum * (1.f / 128.f);
        const float d0 = v0 - mean, d1 = v1 - mean;
        float sq = d0 * d0 + d1 * d1;
        #pragma unroll
        for (int off = 1; off < 64; off <<= 1) sq += __shfl_xor(sq, off, 64);
        const float rstd = rsqrtf(sq * (1.f / 128.f) + LN_EPS);
        float* op = out + (size_t)(pix0 + wid) * DIM;
        op[lane]      = d0 * rstd * gam[lane]      + bet[lane];
        op[lane + 64] = d1 * rstd * gam[lane + 64] + bet[lane + 64];
    }
}

extern "C" void kernel_launch(void* const* d_in, const int* in_sizes, int n_in,
                              void* d_out, int out_size, void* d_ws, size_t ws_size,
                              hipStream_t stream) {
    const float* q    = (const float*)d_in[0];
    const float* kv   = (const float*)d_in[1];
    const float* pos  = (const float*)d_in[2];
    const float* w    = (const float*)d_in[3];
    const float* bias = (const float*)d_in[4];
    const float* gam  = (const float*)d_in[5];
    const float* bet  = (const float*)d_in[6];
    float* out = (float*)d_out;

    const int n_blocks = 2 * IMG * IMG / TILE;   // 1024
    const size_t pad_bytes = (size_t)2 * PDIM * PDIM * DIM * sizeof(float); // 5.6 MB

    if (ws_size >= pad_bytes) {
        float* pkv = (float*)d_ws;
        pad_kernel<<<2 * PDIM * PDIM, 128, 0, stream>>>(kv, pkv);
        nca_kernel<true><<<n_blocks, 512, 0, stream>>>(q, pkv, pos, w, bias, gam, bet, out);
    } else {
        nca_kernel<false><<<n_blocks, 512, 0, stream>>>(q, kv, pos, w, bias, gam, bet, out);
    }
}